// Round 12
// baseline (201.730 us; speedup 1.0000x reference)
//
#include <hip/hip_runtime.h>
#include <hip/hip_bf16.h>
#include <stdint.h>

// Problem: feats[8,1024,32,32]f32, conv_w[256,1024]f32, conv_b[256]f32,
// codebook[16384,256]f32 -> z_q[8,256,32,32]f32 (2097152) + loss scalar.
//
// Round-12 design:
//  - gemm2: LDS shrunk to exactly 32768 B (csh aliased into ldsB after the
//    j-stream) -> 4 blocks/CU if the allocatable-LDS pool is 128 KB (round-11
//    theory for the stuck 3-block occupancy)
//  - gemm1: grid (x=ib 128, y=eb 4) so the 4 eb-blocks sharing an A-tile land
//    on the SAME XCD (delta-linear = 128 = 0 mod 8) -> featsT fetched once

typedef float f32x4 __attribute__((ext_vector_type(4)));
typedef float f32x16 __attribute__((ext_vector_type(16)));
typedef short s16x8 __attribute__((ext_vector_type(8)));

__device__ __forceinline__ void gl2lds16(const void* g, void* l) {
  __builtin_amdgcn_global_load_lds(
      (const __attribute__((address_space(1))) void*)g,
      (__attribute__((address_space(3))) void*)l, 16, 0, 0);
}

__device__ __forceinline__ unsigned short f2bf(float f) {
  unsigned u = __float_as_uint(f);
  u = u + 0x7FFFu + ((u >> 16) & 1u);
  return (unsigned short)(u >> 16);
}
__device__ __forceinline__ float bf2f(unsigned short u) {
  return __uint_as_float(((unsigned)u) << 16);
}

__device__ __forceinline__ ushort4 cvt4(float4 v) {
  ushort4 o;
  o.x = f2bf(v.x); o.y = f2bf(v.y); o.z = f2bf(v.z); o.w = f2bf(v.w);
  return o;
}

// Fused prep, 2432 blocks x 256 thr.
// [0,256):    codebook -> cbs in 32x32x16 A-fragment order. Block jt = 64 j.
//             fl = lp*256+t in [0,2048) maps [ks 16][fr 2][lane 64]:
//             lane holds A[j=jt*64+fr*32+(lane&31)][k=ks*16+(lane>>5)*8 ..+8]
// [256,384):  conv_w -> W2 bf16, 8 elem/thread
// [384,2432): feats [8][1024 c][1024 s] -> featsT bf16 [8192 i][1024 c]
__global__ void k_prep(const float* __restrict__ cbk, const float* __restrict__ Wsrc,
                       const float* __restrict__ feats,
                       unsigned short* __restrict__ cbs, unsigned short* __restrict__ W2,
                       unsigned short* __restrict__ At, float* __restrict__ lossw) {
  __shared__ float tile[64][65];
  int blk = blockIdx.x, t = threadIdx.x;
  if (blk == 0 && t < 2) ((int*)lossw)[t] = 0;
  if (blk < 256) {
    int jt = blk;
    #pragma unroll
    for (int lp = 0; lp < 8; ++lp) {
      int fl = lp * 256 + t;
      int ks = fl >> 7, fr = (fl >> 6) & 1, lane = fl & 63;
      int j = jt * 64 + fr * 32 + (lane & 31);
      int k = ks * 16 + (lane >> 5) * 8;
      const float* src = cbk + (size_t)j * 256 + k;
      float4 v0 = *(const float4*)(src);
      float4 v1 = *(const float4*)(src + 4);
      unsigned short* dst = cbs + ((size_t)jt * 2048 + fl) * 8;
      *(ushort4*)(dst) = cvt4(v0);
      *(ushort4*)(dst + 4) = cvt4(v1);
    }
  } else if (blk < 384) {
    size_t base = (size_t)(blk - 256) * 2048 + t * 8;
    float4 v0 = *(const float4*)(Wsrc + base);
    float4 v1 = *(const float4*)(Wsrc + base + 4);
    *(ushort4*)(W2 + base) = cvt4(v0);
    *(ushort4*)(W2 + base + 4) = cvt4(v1);
  } else {
    int id = blk - 384;
    int b = id >> 8, c0 = ((id >> 4) & 15) * 64, s0 = (id & 15) * 64;
    int tc = t >> 4, ts = (t & 15) * 4;
    #pragma unroll
    for (int k = 0; k < 4; ++k) {
      float4 v = *(const float4*)(feats + ((size_t)b * 1024 + c0 + tc + k * 16) * 1024 + s0 + ts);
      tile[tc + k * 16][ts] = v.x;
      tile[tc + k * 16][ts + 1] = v.y;
      tile[tc + k * 16][ts + 2] = v.z;
      tile[tc + k * 16][ts + 3] = v.w;
    }
    __syncthreads();
    #pragma unroll
    for (int k = 0; k < 4; ++k) {
      int sr = tc + k * 16;
      float4 v;
      v.x = tile[ts][sr]; v.y = tile[ts + 1][sr];
      v.z = tile[ts + 2][sr]; v.w = tile[ts + 3][sr];
      *(ushort4*)(At + (size_t)(b * 1024 + s0 + sr) * 1024 + c0 + ts) = cvt4(v);
    }
  }
}

// GEMM1: z[i][e] = sum_c feats[i][c]*W[e][c] + b[e] (K=1024 bf16) -> zb [i][256].
// BM=BN=64, BK=128, 4 waves 2x2 (wave 32x32), grid (x=128 ib, y=4 eb):
// eb-siblings of one ib land on the same XCD -> A-tile L2 reuse.
__global__ __launch_bounds__(256, 2)
void k_gemm1(const unsigned short* __restrict__ At, const unsigned short* __restrict__ Bw,
             const float* __restrict__ bias, unsigned short* __restrict__ zb) {
  __shared__ __align__(16) uint8_t lds[2048 * 16];
  uint8_t* ldsA = lds;
  uint8_t* ldsB = lds + 1024 * 16;
  const int t = threadIdx.x, w = t >> 6, l = t & 63;
  const int wy = w >> 1, wx = w & 1, l15 = l & 15, q = l >> 4;
  const int ib = blockIdx.x * 64, eb = blockIdx.y * 64;
  f32x4 acc[2][2] = {};
  for (int kt = 0; kt < 8; ++kt) {
    int c0 = kt * 128;
    __syncthreads();
    #pragma unroll
    for (int r = 0; r < 4; ++r) {
      int P = t + 256 * r;  // kp = P>>6 (0..15), m = P&63; LDS layout [kp][m]
      gl2lds16(At + (size_t)(ib + (P & 63)) * 1024 + c0 + (P >> 6) * 8, ldsA + P * 16);
    }
    #pragma unroll
    for (int r = 0; r < 4; ++r) {
      int P = t + 256 * r;
      gl2lds16(Bw + (size_t)(eb + (P & 63)) * 1024 + c0 + (P >> 6) * 8, ldsB + P * 16);
    }
    __syncthreads();
    #pragma unroll
    for (int s = 0; s < 4; ++s) {
      s16x8 a[2], b[2];
      #pragma unroll
      for (int fr = 0; fr < 2; ++fr)
        a[fr] = *(const s16x8*)(ldsA + ((s * 4 + q) * 64 + wy * 32 + fr * 16 + l15) * 16);
      #pragma unroll
      for (int fc = 0; fc < 2; ++fc)
        b[fc] = *(const s16x8*)(ldsB + ((s * 4 + q) * 64 + wx * 32 + fc * 16 + l15) * 16);
      #pragma unroll
      for (int fr = 0; fr < 2; ++fr)
        #pragma unroll
        for (int fc = 0; fc < 2; ++fc)
          acc[fr][fc] = __builtin_amdgcn_mfma_f32_16x16x32_bf16(a[fr], b[fc], acc[fr][fc], 0, 0, 0);
    }
  }
  #pragma unroll
  for (int fc = 0; fc < 2; ++fc) {
    int e = eb + wx * 32 + fc * 16 + l15;
    float bv = bias[e];
    #pragma unroll
    for (int fr = 0; fr < 2; ++fr)
      #pragma unroll
      for (int r = 0; r < 4; ++r) {
        int i = ib + wy * 32 + fr * 16 + q * 4 + r;
        zb[(size_t)i * 256 + e] = f2bf(acc[fr][fc][r] + bv);
      }
  }
}

// GEMM2 + argmax, 32x32x16 j-stream. A = cbs (fragment order),
// B = zb [8192 i][256]. 256 thr / 4 waves, i-tile 64 (LDS exactly 32768 B;
// csh aliased into ldsB after the j-stream). Wave tile 64j x 64i; wave w
// streams jtile = bx*8 + js*4 + w. grid (32 jsplit, 128 ib), XCD = bx%8.
// Fold: p = (bits(3.0+s)<<14) + (16383-j), int-max; 3 VALU/score.
__global__ __launch_bounds__(256, 4)
void k_gemm2(const unsigned short* __restrict__ cbs, const unsigned short* __restrict__ zb,
             int* __restrict__ cand) {
  __shared__ __align__(16) uint8_t ldsB[2048 * 16];  // 32768 B total
  int* csh = (int*)ldsB;                              // aliased, used post-stream
  const int t = threadIdx.x, w = t >> 6, l = t & 63;
  const int l31 = l & 31, h = l >> 5;
  const int ib = blockIdx.y * 64;
  // stage zb tile once: packet P -> i = P&63, kp = P>>6
  #pragma unroll
  for (int r = 0; r < 8; ++r) {
    int P = t + 256 * r;
    gl2lds16(zb + (size_t)(ib + (P & 63)) * 256 + (P >> 6) * 8, ldsB + P * 16);
  }
  int rbest[2];
  rbest[0] = rbest[1] = (int)0x80000000;
  __syncthreads();
  #pragma unroll 1
  for (int js = 0; js < 2; ++js) {
    const int jtile = blockIdx.x * 8 + js * 4 + w;  // 64-j tile index
    const int jw = jtile * 64;
    const uint8_t* abase = (const uint8_t*)cbs + (size_t)jtile * 32768 + l * 16;
    f32x16 acc[2][2] = {};  // [fr j-half][fc i-half]
    #pragma unroll 4
    for (int ks = 0; ks < 16; ++ks) {
      s16x8 a[2], b[2];
      #pragma unroll
      for (int fr = 0; fr < 2; ++fr)
        a[fr] = *(const s16x8*)(abase + (ks * 2 + fr) * 1024);
      #pragma unroll
      for (int fc = 0; fc < 2; ++fc)
        b[fc] = *(const s16x8*)(ldsB + ((ks * 2 + h) * 64 + fc * 32 + l31) * 16);
      #pragma unroll
      for (int fr = 0; fr < 2; ++fr)
        #pragma unroll
        for (int fc = 0; fc < 2; ++fc)
          acc[fr][fc] = __builtin_amdgcn_mfma_f32_32x32x16_bf16(a[fr], b[fc], acc[fr][fc], 0, 0, 0);
    }
    // fold: j = jw + fr*32 + (rg&3) + 8*(rg>>2) + 4*h ; i = ib + fc*32 + l31
    const int encb = 16383 - (jw + 4 * h);
    #pragma unroll
    for (int fc = 0; fc < 2; ++fc) {
      int bb = rbest[fc];
      #pragma unroll
      for (int fr = 0; fr < 2; ++fr) {
        const int e1 = encb - fr * 32;
        #pragma unroll
        for (int rg = 0; rg < 16; ++rg) {
          int e = e1 - ((rg & 3) + 8 * (rg >> 2));
          int m = __float_as_int(3.0f + acc[fr][fc][rg]);  // monotone bits
          int p = (int)(((unsigned)m << 14) + (unsigned)e);
          bb = p > bb ? p : bb;
        }
      }
      rbest[fc] = bb;
    }
  }
  // reduce over h (lane>>5 halves hold disjoint j, same i)
  rbest[0] = max(rbest[0], __shfl_xor(rbest[0], 32, 64));
  rbest[1] = max(rbest[1], __shfl_xor(rbest[1], 32, 64));
  __syncthreads();  // all ldsB reads done; safe to overwrite with csh
  if (l < 32) {
    csh[w * 64 + l31] = rbest[0];
    csh[w * 64 + 32 + l31] = rbest[1];
  }
  __syncthreads();
  if (t < 64) {
    int m0 = max(max(csh[t], csh[64 + t]), max(csh[128 + t], csh[192 + t]));
    cand[(size_t)blockIdx.x * 8192 + ib + t] = m0;
  }
}

// argmin + loss. 128 blocks x 256 thr; block = 64 rows.
// dist_i = ||z_i||^2 - (p>>14)*2^-20. Last block writes the loss scalar.
__global__ void k_argmin(const unsigned short* __restrict__ zb, const int* __restrict__ cand,
                         int* __restrict__ idx, float* __restrict__ lossw,
                         float* __restrict__ out) {
  __shared__ float ps[4];
  int blk = blockIdx.x, t = threadIdx.x;
  int row = t >> 2, c = t & 3;
  int gi = blk * 64 + row;
  // ||z||^2 partial over 64 bf16 elems
  const unsigned short* zrow = zb + (size_t)gi * 256 + c * 64;
  float ss = 0.0f;
  #pragma unroll
  for (int k = 0; k < 64; k += 4) {
    ushort4 v = *(const ushort4*)(zrow + k);
    float a0 = bf2f(v.x), a1 = bf2f(v.y), a2 = bf2f(v.z), a3 = bf2f(v.w);
    ss += a0 * a0 + a1 * a1 + a2 * a2 + a3 * a3;
  }
  // argmax over 32 jsplit partials
  int best = (int)0x80000000;
  #pragma unroll
  for (int k = 0; k < 8; ++k) {
    int v = cand[(size_t)(c + 4 * k) * 8192 + gi];
    best = v > best ? v : best;
  }
  best = max(best, __shfl_xor(best, 1, 64));
  best = max(best, __shfl_xor(best, 2, 64));
  ss += __shfl_xor(ss, 1, 64);
  ss += __shfl_xor(ss, 2, 64);
  float dist = 0.0f;
  if (c == 0) {
    idx[gi] = 16383 - (best & 0x3FFF);
    dist = ss - (float)(best >> 14) * (1.0f / 1048576.0f);  // 2*score
  }
  float v = dist;
  #pragma unroll
  for (int m = 32; m; m >>= 1) v += __shfl_down(v, m, 64);
  if ((t & 63) == 0) ps[t >> 6] = v;
  __syncthreads();
  if (t == 0) {
    float part = ps[0] + ps[1] + ps[2] + ps[3];
    atomicAdd(lossw, part);
    __threadfence();
    int cnt = atomicAdd((int*)lossw + 1, 1);
    if (cnt == 127) {
      __threadfence();
      float total = atomicAdd(lossw, 0.0f);
      out[2097152] = 1.25f * total * (1.0f / 2097152.0f);
    }
  }
}

// Output gather, LDS-staged. 256 blocks x 256 thr; block = (b, s0) = 32 rows.
// Phase A: codebook rows in 256B bursts -> tile[32][257]. Phase B: contiguous
// 128B out writes, conflict-free LDS reads (pad 257).
__global__ void k_gather(const float* __restrict__ cbk, const int* __restrict__ idx,
                         float* __restrict__ out) {
  __shared__ float tile[32][257];
  __shared__ int lidx[32];
  int blk = blockIdx.x, t = threadIdx.x;
  int b = blk >> 5, s0 = (blk & 31) * 32;
  if (t < 32) lidx[t] = idx[b * 1024 + s0 + t];
  __syncthreads();
  int w = t >> 6, l = t & 63;
  #pragma unroll
  for (int rr = 0; rr < 8; ++rr) {
    int r = w * 8 + rr;
    const float* src = cbk + (size_t)lidx[r] * 256;
    #pragma unroll
    for (int k = 0; k < 4; ++k)
      tile[r][l + 64 * k] = src[l + 64 * k];
  }
  __syncthreads();
  int sl = t & 31, eg = t >> 5;  // eg 0..7
  size_t ob = (size_t)b * 262144 + s0 + sl;
  #pragma unroll
  for (int k = 0; k < 32; ++k) {
    int e = eg + 8 * k;
    out[ob + (size_t)e * 1024] = tile[sl][e];
  }
}

extern "C" void kernel_launch(void* const* d_in, const int* in_sizes, int n_in,
                              void* d_out, int out_size, void* d_ws, size_t ws_size,
                              hipStream_t stream) {
  const float* feats  = (const float*)d_in[0];
  const float* conv_w = (const float*)d_in[1];
  const float* conv_b = (const float*)d_in[2];
  const float* cbk    = (const float*)d_in[3];
  float* out = (float*)d_out;
  char* ws = (char*)d_ws;
  // workspace layout (bytes), ~31 MB total
  unsigned short* featsT = (unsigned short*)(ws);                  // 16,777,216
  unsigned short* W2     = (unsigned short*)(ws + 16777216);       //    524,288
  unsigned short* cbs    = (unsigned short*)(ws + 17301504);       //  8,388,608
  unsigned short* zb     = (unsigned short*)(ws + 25690112);       //  4,194,304
  int*            cand   = (int*)(ws + 29884416);                  //  1,048,576
  int*            idx    = (int*)(ws + 30932992);                  //     32,768
  float*          lossw  = (float*)(ws + 30965760);                //        256

  k_prep<<<2432, 256, 0, stream>>>(cbk, conv_w, feats, cbs, W2, featsT, lossw);
  k_gemm1<<<dim3(128, 4), 256, 0, stream>>>(featsT, W2, conv_b, zb);
  k_gemm2<<<dim3(32, 128), 256, 0, stream>>>(cbs, zb, cand);
  k_argmin<<<128, 256, 0, stream>>>(zb, cand, idx, lossw, out);
  k_gather<<<256, 256, 0, stream>>>(cbk, idx, out);
}